// Round 1
// 858.312 us; speedup vs baseline: 1.0694x; 1.0694x over previous
//
#include <hip/hip_runtime.h>

#define DEV __device__ __forceinline__

typedef short bf16x8 __attribute__((ext_vector_type(8)));
typedef float f32x4 __attribute__((ext_vector_type(4)));

static const int NVOX = 262144; // 64^3

DEV float bflo(unsigned int u) { return __uint_as_float(u << 16); }
DEV float bfhi(unsigned int u) { return __uint_as_float(u & 0xffff0000u); }
DEV float bf2f(unsigned short s) { return __uint_as_float(((unsigned int)s) << 16); }
DEV unsigned short f2bf(float f) {
    unsigned int x = __float_as_uint(f);
    x += 0x7fffu + ((x >> 16) & 1u);   // RNE
    return (unsigned short)(x >> 16);
}
// dual-dtype raw-input load: f==1 -> fp32, f==0 -> bf16
DEV float ldin(const void* p, int i, int f) {
    return f ? ((const float*)p)[i] : bf2f(((const unsigned short*)p)[i]);
}

// ---------------------------------------------------------------------------
// Dtype sniffer (insurance; R3 confirmed fp32 inputs).
// ---------------------------------------------------------------------------
__global__ void sniff_kernel(const unsigned short* __restrict__ src, int* __restrict__ flag) {
    __shared__ int cnt[256];
    int t = threadIdx.x;
    int c = 0;
    for (int i = t; i < 4096; i += 256) {
        unsigned int u = (unsigned int)src[i] & 0x7fffu;
        c += (u >= 0x4900u) ? 1 : 0;
    }
    cnt[t] = c;
    __syncthreads();
    for (int s = 128; s > 0; s >>= 1) {
        if (t < s) cnt[t] += cnt[t + s];
        __syncthreads();
    }
    if (t == 0) *flag = (cnt[0] > 8) ? 1 : 0;
}

// ---------------------------------------------------------------------------
// Weight prep into MFMA B-fragment order:
//   Wf[tap][kc][nt][lane][j]  (j=0..7, lane=0..63), 512 shorts per fragment.
//   Fragment element (lane,j) = W[o = nt*16 + (lane&15)][cp = kc*32 + (lane>>4)*8 + j]
// ---------------------------------------------------------------------------
__global__ void prep_kernel(const void* __restrict__ w1, const void* __restrict__ w2,
                            const void* __restrict__ bsv, const void* __restrict__ btv,
                            const void* __restrict__ b1v, const void* __restrict__ b2v,
                            const int* __restrict__ flag,
                            unsigned short* __restrict__ Wf1,
                            unsigned short* __restrict__ Wf2,
                            float* __restrict__ fbias) {
    const int f = *flag;
    int idx = blockIdx.x * 256 + threadIdx.x;
    const int N1 = 27 * 5 * 4 * 512;   // 276480
    const int N2 = 27 * 2 * 4 * 512;   // 110592
    if (idx < N1) {
        int frag = idx >> 9;           // (tap*5 + kc)*4 + nt
        int r    = idx & 511;
        int lane = r >> 3, j = r & 7;
        int nt = frag & 3;
        int tk = frag >> 2;            // tap*5 + kc
        int tap = tk / 5, kc = tk % 5;
        int o  = nt * 16 + (lane & 15);
        int cp = kc * 32 + (lane >> 4) * 8 + j;
        unsigned short val = 0;
        if (cp < 130) val = f2bf(ldin(w1, (o * 130 + cp) * 27 + tap, f));
        Wf1[idx] = val;
    } else if (idx < N1 + N2) {
        int i2 = idx - N1;
        int frag = i2 >> 9;            // (tap*2 + kc)*4 + nt
        int r    = i2 & 511;
        int lane = r >> 3, j = r & 7;
        int nt = frag & 3;
        int tk = frag >> 2;
        int tap = tk >> 1, kc = tk & 1;
        int o = nt * 16 + (lane & 15);
        int c = kc * 32 + (lane >> 4) * 8 + j;
        Wf2[i2] = f2bf(ldin(w2, (o * 64 + c) * 27 + tap, f));
    } else if (idx < N1 + N2 + 256) {
        int j = idx - N1 - N2;
        const void* bp = (j < 64) ? bsv : (j < 128) ? btv : (j < 192) ? b1v : b2v;
        fbias[j] = ldin(bp, j & 63, f);
    }
}

// ---------------------------------------------------------------------------
// Projection (1x1x1 conv 32->64) + L2 normalize over channels.
// ---------------------------------------------------------------------------
__global__ __launch_bounds__(256) void proj_kernel(
        const void* __restrict__ Xsrc, const void* __restrict__ Xtgt,
        const void* __restrict__ Wsrc, const void* __restrict__ Wtgt,
        const float* __restrict__ fbias, const int* __restrict__ flag,
        unsigned short* __restrict__ SP, unsigned short* __restrict__ TP) {
    const int f = *flag;
    const void* Xin = blockIdx.y ? Xtgt : Xsrc;
    const void* W   = blockIdx.y ? Wtgt : Wsrc;
    const float* Bb = fbias + (blockIdx.y ? 64 : 0);
    unsigned short* Outp = blockIdx.y ? TP : SP;

    __shared__ float ws[2048];   // [ci][o]
    const int t = threadIdx.x;
    for (int i = t; i < 2048; i += 256) {
        int ci = i >> 6, o = i & 63;
        ws[i] = ldin(W, o * 32 + ci, f);
    }
    __syncthreads();

    const size_t v = (size_t)blockIdx.x * 256 + t;
    float acc[64];
#pragma unroll
    for (int o = 0; o < 64; ++o) acc[o] = Bb[o];
    if (f) {
        const float* Xf = (const float*)Xin;
        for (int ci = 0; ci < 32; ++ci) {
            float x = Xf[(size_t)ci * NVOX + v];
            const float4* wr = (const float4*)(ws + ci * 64);
#pragma unroll
            for (int o4 = 0; o4 < 16; ++o4) {
                float4 w4 = wr[o4];
                acc[o4 * 4 + 0] = fmaf(w4.x, x, acc[o4 * 4 + 0]);
                acc[o4 * 4 + 1] = fmaf(w4.y, x, acc[o4 * 4 + 1]);
                acc[o4 * 4 + 2] = fmaf(w4.z, x, acc[o4 * 4 + 2]);
                acc[o4 * 4 + 3] = fmaf(w4.w, x, acc[o4 * 4 + 3]);
            }
        }
    } else {
        const unsigned short* Xb = (const unsigned short*)Xin;
        for (int ci = 0; ci < 32; ++ci) {
            float x = bf2f(Xb[(size_t)ci * NVOX + v]);
            const float4* wr = (const float4*)(ws + ci * 64);
#pragma unroll
            for (int o4 = 0; o4 < 16; ++o4) {
                float4 w4 = wr[o4];
                acc[o4 * 4 + 0] = fmaf(w4.x, x, acc[o4 * 4 + 0]);
                acc[o4 * 4 + 1] = fmaf(w4.y, x, acc[o4 * 4 + 1]);
                acc[o4 * 4 + 2] = fmaf(w4.z, x, acc[o4 * 4 + 2]);
                acc[o4 * 4 + 3] = fmaf(w4.w, x, acc[o4 * 4 + 3]);
            }
        }
    }
    float s = 0.f;
#pragma unroll
    for (int o = 0; o < 64; ++o) s = fmaf(acc[o], acc[o], s);
    float scale = 1.f / fmaxf(sqrtf(s), 1e-12f);

    unsigned int pk[32];
#pragma unroll
    for (int o = 0; o < 32; ++o)
        pk[o] = (unsigned int)f2bf(acc[2 * o] * scale) |
                ((unsigned int)f2bf(acc[2 * o + 1] * scale) << 16);
    uint4* outp = (uint4*)(Outp + v * 64);
#pragma unroll
    for (int j = 0; j < 8; ++j)
        outp[j] = make_uint4(pk[4 * j], pk[4 * j + 1], pk[4 * j + 2], pk[4 * j + 3]);
}

// ---------------------------------------------------------------------------
// Correlation via MFMA (banded implicit GEMM) + exact fp32 online softmax.
//
// Block = one x-row (z,y fixed): 64 voxels. Wave w owns m-tile w (x0=16w).
// Per (dz,dy) of 25: stage clamped TP row [80 pos][64ch] bf16 in LDS
// (XOR-swizzled chunks to avoid 128B-stride bank conflicts, double-buffered
// with register prefetch), then C[16x][32p] = SP_tile * TP_tile^T via
// 4x mfma_f32_16x16x32_bf16 per wave; extract the |p-x|<=2 band into
//   - stage[v][168] bf16 (enc_in assembly, unchanged layout), and
//   - band[64][5] fp32 for the per-voxel online softmax (threads t<64),
// preserving the previous kernel's exact fp32 softmax numerics and k-order.
// XCD-aware swizzle: each XCD gets 8 contiguous z-slices so the concurrent
// TP neighborhood (~2.8MB) stays resident in its 4MiB L2.
// ---------------------------------------------------------------------------
DEV void tp_load(const unsigned short* __restrict__ TP, int t, int z, int y,
                 int it, uint4* pre) {
    const int zc = min(max(z + it / 5 - 2, 0), 63);
    const int yc = min(max(y + it % 5 - 2, 0), 63);
    const unsigned short* tbase = TP + ((size_t)zc * 64 + yc) * 4096;
#pragma unroll
    for (int j = 0; j < 3; ++j) {
        int i = t + j * 256;
        uint4 vv = make_uint4(0u, 0u, 0u, 0u);
        if (i < 640) {
            int pp = i >> 3, cc = i & 7;
            int xc = min(max(pp - 2, 0), 63);
            vv = *(const uint4*)(tbase + xc * 64 + cc * 8);
        }
        pre[j] = vv;
    }
}

DEV void tp_commit(unsigned short* buf, int t, const uint4* pre) {
#pragma unroll
    for (int j = 0; j < 3; ++j) {
        int i = t + j * 256;
        if (i < 640) {
            int pp = i >> 3, cc = i & 7;
            *(uint4*)((char*)buf + pp * 128 + ((cc ^ (pp & 7)) * 16)) = pre[j];
        }
    }
}

__global__ __launch_bounds__(256) void corr_kernel(
        const unsigned short* __restrict__ SP, const unsigned short* __restrict__ TP,
        unsigned short* __restrict__ X1, float* __restrict__ Out) {
    __shared__ __align__(16) unsigned short spb[64 * 64];      //  8192 B (swizzled)
    __shared__ __align__(16) unsigned short tpb[2][80 * 64];   // 20480 B (swizzled)
    __shared__ __align__(16) unsigned short stage[64 * 168];   // 21504 B
    __shared__ __align__(16) float band[64 * 5];               //  1280 B

    const int t = threadIdx.x;
    const int wv = t >> 6, lane = t & 63;
    const int q = lane >> 4, l16 = lane & 15;
    const int x0 = wv * 16;

    // XCD-aware bijective swizzle: XCD k gets z-slices [8k, 8k+8)
    const int bid = blockIdx.x;
    const int wg = (bid & 7) * 512 + (bid >> 3);
    const int z = wg >> 6, y = wg & 63;
    const size_t vbase = ((size_t)z * 64 + y) * 64;

    // --- SP row load (512 x 16B chunks, 2/thread) ---
    uint4 spv0, spv1;
    {
        int i0 = t, i1 = t + 256;
        spv0 = *(const uint4*)(SP + (vbase + (i0 >> 3)) * 64 + (i0 & 7) * 8);
        spv1 = *(const uint4*)(SP + (vbase + (i1 >> 3)) * 64 + (i1 & 7) * 8);
    }
    // zero stage padding cols [128,160)
    {
        int vox = t >> 2, c4 = t & 3;
        *(uint4*)(&stage[vox * 168 + 128 + c4 * 8]) = make_uint4(0u, 0u, 0u, 0u);
    }
    // commit SP to LDS (swizzled)
    {
        int i0 = t, i1 = t + 256;
        int xa = i0 >> 3, ca = i0 & 7;
        int xb = i1 >> 3, cb = i1 & 7;
        *(uint4*)((char*)spb + xa * 128 + ((ca ^ (xa & 7)) * 16)) = spv0;
        *(uint4*)((char*)spb + xb * 128 + ((cb ^ (xb & 7)) * 16)) = spv1;
    }

    // online softmax state (valid for t<64, voxel = t)
    float m = -1e30f, s2 = -1e30f, Zs = 0.f, S1 = 0.f, Ox = 0.f, Oy = 0.f, Oz = 0.f;

    uint4 pre[3];
    tp_load(TP, t, z, y, 0, pre);
    int p = 0;
    for (int it = 0; it < 25; ++it) {
        tp_commit(tpb[p], t, pre);
        __syncthreads();                         // barrier A
        if (it < 24) tp_load(TP, t, z, y, it + 1, pre);

        f32x4 acc[2] = {{0.f, 0.f, 0.f, 0.f}, {0.f, 0.f, 0.f, 0.f}};
        {
            const char* sb = (const char*)spb;
            const char* tb = (const char*)tpb[p];
            const int xr = x0 + l16;
#pragma unroll
            for (int kc = 0; kc < 2; ++kc) {
                bf16x8 a = *(const bf16x8*)(sb + xr * 128 + (((kc * 4 + q) ^ (xr & 7)) * 16));
#pragma unroll
                for (int nt = 0; nt < 2; ++nt) {
                    const int pr = x0 + nt * 16 + l16;
                    bf16x8 b = *(const bf16x8*)(tb + pr * 128 + (((kc * 4 + q) ^ (pr & 7)) * 16));
                    acc[nt] = __builtin_amdgcn_mfma_f32_16x16x32_bf16(a, b, acc[nt], 0, 0, 0);
                }
            }
        }
        // band extraction: C row (m) = q*4+r, col (n) = l16; dx = nt*16+l16-2-(q*4+r)
        const int kb = it * 5;
#pragma unroll
        for (int nt = 0; nt < 2; ++nt) {
#pragma unroll
            for (int r = 0; r < 4; ++r) {
                int ml = q * 4 + r;
                int dxp = nt * 16 + l16 - ml;     // dx + 2
                if ((unsigned)dxp < 5u) {
                    int xl = x0 + ml;
                    float d = acc[nt][r];
                    band[xl * 5 + dxp] = d;
                    stage[xl * 168 + kb + dxp] = f2bf(d);
                }
            }
        }
        __syncthreads();                         // barrier B
        if (t < 64) {
            const float fz = (float)(it / 5 - 2), fy = (float)(it % 5 - 2);
#pragma unroll
            for (int dxp = 0; dxp < 5; ++dxp) {
                float d = band[t * 5 + dxp];
                float fx = (float)(dxp - 2);
                if (d > m) {
                    float sc = __expf(m - d);
                    Zs = fmaf(Zs, sc, 1.f); S1 = fmaf(S1, sc, d);
                    Ox = fmaf(Ox, sc, fx); Oy = fmaf(Oy, sc, fy); Oz = fmaf(Oz, sc, fz);
                    s2 = m; m = d;
                } else {
                    float e = __expf(d - m);
                    Zs += e; S1 = fmaf(e, d, S1);
                    Ox = fmaf(e, fx, Ox); Oy = fmaf(e, fy, Oy); Oz = fmaf(e, fz, Oz);
                    s2 = fmaxf(s2, d);
                }
            }
        }
        p ^= 1;
    }

    if (t < 64) {
        float inv  = 1.f / fmaxf(Zs, 1e-8f);
        float eoz = Oz * inv, eoy = Oy * inv, eox = Ox * inv;
        float conf = fminf(inv, 1.f);
        float marg = fmaxf(conf - __expf(s2 - m) * inv, 0.f);
        float ent  = m + __logf(fmaxf(Zs, 1e-8f)) - S1 * inv;
        stage[t * 168 + 125] = f2bf(eoz);
        stage[t * 168 + 126] = f2bf(eoy);
        stage[t * 168 + 127] = f2bf(eox);
        stage[t * 168 + 128] = f2bf(conf);
        stage[t * 168 + 129] = f2bf(ent);
        const size_t v = vbase + t;
        Out[v]                    = eoz;
        Out[(size_t)NVOX + v]     = eoy;
        Out[(size_t)2 * NVOX + v] = eox;
        Out[(size_t)3 * NVOX + v] = conf;
        Out[(size_t)4 * NVOX + v] = marg;
        Out[(size_t)5 * NVOX + v] = ent;
    }
    __syncthreads();

    // X1 assembly: 64 vox x 20 uint4
#pragma unroll
    for (int j = 0; j < 5; ++j) {
        int i = t + j * 256;
        int vox = i / 20, cc = i % 20;
        *(uint4*)(X1 + (vbase + vox) * 160 + (size_t)cc * 8) =
            *(const uint4*)(&stage[vox * 168 + cc * 8]);
    }
}

// ---------------------------------------------------------------------------
// 3x3x3 conv, implicit GEMM via mfma_f32_16x16x32_bf16, zero padding.
// Block = one (z,y) x-row: 64 voxels x 64 out-ch.
// Hybrid 2x2 wave tiling: wave owns 2 M-tiles x 2 N-tiles (balances B global
// traffic vs A LDS traffic). Double-buffered staging, one barrier per
// (dz,dy) iteration, next iteration's rows prefetched into registers during
// MFMA. Invalid halo rows stage zeros (zero-pad conv => harmless MFMAs) so
// all blocks run a uniform 9-iteration loop.
// ---------------------------------------------------------------------------
template <int CPAD, int LSTRIDE, int KC, int NLD>
__global__ __launch_bounds__(256) void conv3_kernel(
        const unsigned short* __restrict__ Xin, const unsigned short* __restrict__ Wf,
        const float* __restrict__ Bias, unsigned short* __restrict__ Out) {
    __shared__ unsigned short rowbuf[2][66 * LSTRIDE];
    const int lin = blockIdx.x;
    const int z = (lin & 7) * 8 + ((lin >> 3) >> 6);
    const int y = (lin >> 3) & 63;
    const int t = threadIdx.x;
    const int wv = t >> 6, lane = t & 63;
    const int quad = lane >> 4, l16 = lane & 15;
    const int mt2 = (wv & 1) * 2;    // m-tile pair base
    const int nt2 = (wv >> 1) * 2;   // n-tile pair base
    const int CH16 = CPAD / 8;

    f32x4 acc[2][2] = {{{0.f,0.f,0.f,0.f},{0.f,0.f,0.f,0.f}},
                       {{0.f,0.f,0.f,0.f},{0.f,0.f,0.f,0.f}}};

    uint4 pre[NLD];
    // prologue: loads for iteration 0 (dz=-1, dy=-1)
    {
        const int zz = z - 1, yy = y - 1;
        const bool valid = (unsigned)zz < 64u && (unsigned)yy < 64u;
        const unsigned short* base = Xin + (((size_t)(valid ? zz : 0) * 64 + (valid ? yy : 0)) * 64) * CPAD;
#pragma unroll
        for (int i = 0; i < NLD; ++i) {
            int idx = t + i * 256;
            uint4 val = make_uint4(0u, 0u, 0u, 0u);
            if (idx < 66 * CH16) {
                int xi = idx / CH16, ci = idx % CH16;
                int gx = xi - 1;
                if (valid && gx >= 0 && gx < 64) val = *(const uint4*)(base + gx * CPAD + ci * 8);
            }
            pre[i] = val;
        }
    }

    int p = 0;
    for (int it = 0; it < 9; ++it) {
        // commit prefetched rows into LDS buffer p
#pragma unroll
        for (int i = 0; i < NLD; ++i) {
            int idx = t + i * 256;
            if (idx < 66 * CH16) {
                int xi = idx / CH16, ci = idx % CH16;
                *(uint4*)(&rowbuf[p][xi * LSTRIDE + ci * 8]) = pre[i];
            }
        }
        __syncthreads();
        // issue next iteration's loads (overlaps the MFMA work below)
        if (it < 8) {
            const int itn = it + 1;
            const int zz = z + itn / 3 - 1, yy = y + itn % 3 - 1;
            const bool valid = (unsigned)zz < 64u && (unsigned)yy < 64u;
            const unsigned short* base = Xin + (((size_t)(valid ? zz : 0) * 64 + (valid ? yy : 0)) * 64) * CPAD;
#pragma unroll
            for (int i = 0; i < NLD; ++i) {
                int idx = t + i * 256;
                uint4 val = make_uint4(0u, 0u, 0u, 0u);
                if (idx < 66 * CH16) {
                    int xi = idx / CH16, ci = idx % CH16;
                    int gx = xi - 1;
                    if (valid && gx >= 0 && gx < 64) val = *(const uint4*)(base + gx * CPAD + ci * 8);
                }
                pre[i] = val;
            }
        }
        const unsigned short* rp = rowbuf[p];
#pragma unroll
        for (int dx = 0; dx < 3; ++dx) {
            const int tap = it * 3 + dx;
            const unsigned short* wt = Wf + ((size_t)tap * KC * 4) * 512 + lane * 8;
            bf16x8 bf[KC][2];
#pragma unroll
            for (int kc = 0; kc < KC; ++kc)
#pragma unroll
                for (int nl = 0; nl < 2; ++nl)
                    bf[kc][nl] = *(const bf16x8*)(wt + (size_t)(kc * 4 + nt2 + nl) * 512);
#pragma unroll
            for (int kc = 0; kc < KC; ++kc) {
#pragma unroll
                for (int ml = 0; ml < 2; ++ml) {
                    bf16x8 a = *(const bf16x8*)(&rp[((mt2 + ml) * 16 + l16 + dx) * LSTRIDE + kc * 32 + quad * 8]);
#pragma unroll
                    for (int nl = 0; nl < 2; ++nl)
                        acc[ml][nl] = __builtin_amdgcn_mfma_f32_16x16x32_bf16(a, bf[kc][nl], acc[ml][nl], 0, 0, 0);
                }
            }
        }
        p ^= 1;
    }

    const size_t vbase = ((size_t)z * 64 + y) * 64;
#pragma unroll
    for (int ml = 0; ml < 2; ++ml) {
#pragma unroll
        for (int nl = 0; nl < 2; ++nl) {
            const int oc = (nt2 + nl) * 16 + l16;
            const float bv = Bias[oc];
#pragma unroll
            for (int r = 0; r < 4; ++r)
                Out[(vbase + (mt2 + ml) * 16 + quad * 4 + r) * 64 + oc] = f2bf(acc[ml][nl][r] + bv);
        }
    }
}

// ---------------------------------------------------------------------------
// Per-channel sum / sumsq over all voxels (InstanceNorm stats).
// ---------------------------------------------------------------------------
__global__ __launch_bounds__(256) void stats_kernel(
        const unsigned short* __restrict__ H, float* __restrict__ stats) {
    const int t = threadIdx.x;
    const int c = t & 63, g = t >> 6;
    float s = 0.f, q = 0.f;
    for (int v = blockIdx.x * 4 + g; v < NVOX; v += gridDim.x * 4) {
        float x = bf2f(H[(size_t)v * 64 + c]);
        s += x; q = fmaf(x, x, q);
    }
    __shared__ float ls[256], lq[256];
    ls[t] = s; lq[t] = q;
    __syncthreads();
    if (t < 64) {
        s = ls[t] + ls[t + 64] + ls[t + 128] + ls[t + 192];
        q = lq[t] + lq[t + 64] + lq[t + 128] + lq[t + 192];
        atomicAdd(&stats[c], s);
        atomicAdd(&stats[64 + c], q);
    }
}

__global__ void finalize_kernel(const float* __restrict__ stats, float* __restrict__ musr) {
    int c = threadIdx.x;
    if (c < 64) {
        float mu  = stats[c] * (1.0f / 262144.0f);
        float var = stats[64 + c] * (1.0f / 262144.0f) - mu * mu;
        musr[c] = mu;
        musr[64 + c] = rsqrtf(var + 1e-5f);
    }
}

// ---------------------------------------------------------------------------
// Elementwise InstanceNorm + exact GELU, [v][64] -> [v][64] bf16
// ---------------------------------------------------------------------------
__global__ __launch_bounds__(256) void norm_gelu_kernel(
        const unsigned short* __restrict__ H, const float* __restrict__ musr,
        unsigned short* __restrict__ G) {
    const size_t base = ((size_t)blockIdx.x * 256 + threadIdx.x) * 8;
    uint4 u = *(const uint4*)(H + base);
    const int c0 = (int)(base & 63);
    const unsigned int uu[4] = {u.x, u.y, u.z, u.w};
    unsigned int w[4];
#pragma unroll
    for (int p = 0; p < 4; ++p) {
        int c = c0 + p * 2;
        float x0 = (bflo(uu[p]) - musr[c]) * musr[64 + c];
        float x1 = (bfhi(uu[p]) - musr[c + 1]) * musr[64 + c + 1];
        float g0 = 0.5f * x0 * (1.f + erff(x0 * 0.70710678118f));
        float g1 = 0.5f * x1 * (1.f + erff(x1 * 0.70710678118f));
        w[p] = (unsigned int)f2bf(g0) | ((unsigned int)f2bf(g1) << 16);
    }
    *(uint4*)(G + base) = make_uint4(w[0], w[1], w[2], w[3]);
}

// ---------------------------------------------------------------------------
// Final: InstanceNorm + exact GELU on h2, write fp32 channel planes [64][v].
// ---------------------------------------------------------------------------
__global__ __launch_bounds__(256) void out_final_kernel(
        const unsigned short* __restrict__ H2, const float* __restrict__ musr,
        float* __restrict__ OutEnc) {
    __shared__ float tile[64 * 260];
    const int t = threadIdx.x;
    const size_t v0 = (size_t)blockIdx.x * 256;
#pragma unroll
    for (int i = 0; i < 8; ++i) {
        int chunk = t + i * 256;                  // 0..2047
        uint4 u = *(const uint4*)(H2 + v0 * 64 + (size_t)chunk * 8);
        int vox = chunk >> 3;
        int c0 = (chunk & 7) * 8;
        const unsigned int uu[4] = {u.x, u.y, u.z, u.w};
#pragma unroll
        for (int p = 0; p < 4; ++p) {
            int c = c0 + p * 2;
            float x0 = (bflo(uu[p]) - musr[c]) * musr[64 + c];
            float x1 = (bfhi(uu[p]) - musr[c + 1]) * musr[64 + c + 1];
            tile[c * 260 + vox]       = 0.5f * x0 * (1.f + erff(x0 * 0.70710678118f));
            tile[(c + 1) * 260 + vox] = 0.5f * x1 * (1.f + erff(x1 * 0.70710678118f));
        }
    }
    __syncthreads();
    const int c = t >> 2, sub = t & 3;
#pragma unroll
    for (int iter = 0; iter < 16; ++iter) {
        int fq = iter * 4 + sub;                  // float4 index 0..63
        float4 val = *(const float4*)(&tile[c * 260 + fq * 4]);
        *(float4*)(OutEnc + (size_t)c * NVOX + v0 + fq * 4) = val;
    }
}

// ---------------------------------------------------------------------------
extern "C" void kernel_launch(void* const* d_in, const int* in_sizes, int n_in,
                              void* d_out, int out_size, void* d_ws, size_t ws_size,
                              hipStream_t stream) {
    const void* src  = d_in[0];
    const void* tgt  = d_in[1];
    const void* wsrc = d_in[2];
    const void* bsrc = d_in[3];
    const void* wtgt = d_in[4];
    const void* btgt = d_in[5];
    const void* w1   = d_in[6];
    const void* b1   = d_in[7];
    const void* w2   = d_in[8];
    const void* b2   = d_in[9];
    float* out = (float*)d_out;   // fp32 outputs, 70*262144 elements

    char* ws = (char*)d_ws;
    unsigned short* TPb = (unsigned short*)(ws);                  // 33,554,432 B
    unsigned short* SPb = (unsigned short*)(ws + 33554432);       // 33,554,432 B
    unsigned short* X1  = (unsigned short*)(ws + 67108864);       // 83,886,080 B
    unsigned short* Wf1 = (unsigned short*)(ws + 150994944);      //    552,960 B
    unsigned short* Wf2 = (unsigned short*)(ws + 151547904);      //    221,184 B
    int*   flag   = (int*)  (ws + 151769088);
    float* fbias  = (float*)(ws + 151769152);                     // 256 f32
    float* stats1 = (float*)(ws + 151770176);                     // 128 f32
    float* musr1  = (float*)(ws + 151770688);
    float* stats2 = (float*)(ws + 151771200);
    float* musr2  = (float*)(ws + 151771712);
    unsigned short* H1 = SPb;
    unsigned short* G1 = TPb;
    unsigned short* H2 = X1;

    (void)hipMemsetAsync(stats1, 0, 2048, stream);
    sniff_kernel<<<1, 256, 0, stream>>>((const unsigned short*)src, flag);
    prep_kernel<<<1513, 256, 0, stream>>>(w1, w2, bsrc, btgt, b1, b2, flag, Wf1, Wf2, fbias);
    proj_kernel<<<dim3(1024, 2), 256, 0, stream>>>(src, tgt, wsrc, wtgt, fbias, flag, SPb, TPb);
    corr_kernel<<<4096, 256, 0, stream>>>(SPb, TPb, X1, out);
    conv3_kernel<160, 168, 5, 6><<<4096, 256, 0, stream>>>(X1, Wf1, fbias + 128, H1);
    stats_kernel<<<256, 256, 0, stream>>>(H1, stats1);
    finalize_kernel<<<1, 64, 0, stream>>>(stats1, musr1);
    norm_gelu_kernel<<<8192, 256, 0, stream>>>(H1, musr1, G1);
    conv3_kernel<64, 72, 2, 3><<<4096, 256, 0, stream>>>(G1, Wf2, fbias + 192, H2);
    stats_kernel<<<256, 256, 0, stream>>>(H2, stats2);
    finalize_kernel<<<1, 64, 0, stream>>>(stats2, musr2);
    out_final_kernel<<<1024, 256, 0, stream>>>(H2, musr2, out + 6 * (size_t)NVOX);
}

// Round 2
// 794.334 us; speedup vs baseline: 1.1556x; 1.0805x over previous
//
#include <hip/hip_runtime.h>

#define DEV __device__ __forceinline__

typedef short bf16x8 __attribute__((ext_vector_type(8)));
typedef float f32x4 __attribute__((ext_vector_type(4)));

static const int NVOX = 262144; // 64^3

DEV float bflo(unsigned int u) { return __uint_as_float(u << 16); }
DEV float bfhi(unsigned int u) { return __uint_as_float(u & 0xffff0000u); }
DEV float bf2f(unsigned short s) { return __uint_as_float(((unsigned int)s) << 16); }
DEV unsigned short f2bf(float f) {
    unsigned int x = __float_as_uint(f);
    x += 0x7fffu + ((x >> 16) & 1u);   // RNE
    return (unsigned short)(x >> 16);
}
// dual-dtype raw-input load: f==1 -> fp32, f==0 -> bf16
DEV float ldin(const void* p, int i, int f) {
    return f ? ((const float*)p)[i] : bf2f(((const unsigned short*)p)[i]);
}

// ---------------------------------------------------------------------------
// Dtype sniffer (insurance; fp32 inputs confirmed).
// ---------------------------------------------------------------------------
__global__ void sniff_kernel(const unsigned short* __restrict__ src, int* __restrict__ flag) {
    __shared__ int cnt[256];
    int t = threadIdx.x;
    int c = 0;
    for (int i = t; i < 4096; i += 256) {
        unsigned int u = (unsigned int)src[i] & 0x7fffu;
        c += (u >= 0x4900u) ? 1 : 0;
    }
    cnt[t] = c;
    __syncthreads();
    for (int s = 128; s > 0; s >>= 1) {
        if (t < s) cnt[t] += cnt[t + s];
        __syncthreads();
    }
    if (t == 0) *flag = (cnt[0] > 8) ? 1 : 0;
}

// ---------------------------------------------------------------------------
// Weight prep into MFMA B-fragment order:
//   Wf1: conv1 main K-chunks, ch 0..127:  [tap][kc<4][nt][lane][j], 512 sh/frag
//   Wf1e: conv1 tail (ch 128..129 x 27 taps -> K=54 pad 64): [kc<2][nt][lane][j]
//   Wf2: conv2, K=64: [tap][kc<2][nt][lane][j]
//   Fragment element (lane,j) = W[o = nt*16 + (lane&15)][k = kc*32 + (lane>>4)*8 + j]
// ---------------------------------------------------------------------------
__global__ void prep_kernel(const void* __restrict__ w1, const void* __restrict__ w2,
                            const void* __restrict__ bsv, const void* __restrict__ btv,
                            const void* __restrict__ b1v, const void* __restrict__ b2v,
                            const int* __restrict__ flag,
                            unsigned short* __restrict__ Wf1,
                            unsigned short* __restrict__ Wf2,
                            float* __restrict__ fbias) {
    const int f = *flag;
    int idx = blockIdx.x * 256 + threadIdx.x;
    const int N1  = 27 * 4 * 4 * 512;   // 221184 (main, kc<4)
    const int N1E = 2 * 4 * 512;        //   4096 (tail)
    const int N2  = 27 * 2 * 4 * 512;   // 110592
    if (idx < N1) {
        int frag = idx >> 9;           // (tap*4 + kc)*4 + nt
        int r    = idx & 511;
        int lane = r >> 3, j = r & 7;
        int nt = frag & 3;
        int tk = frag >> 2;            // tap*4 + kc
        int tap = tk >> 2, kc = tk & 3;
        int o  = nt * 16 + (lane & 15);
        int cp = kc * 32 + (lane >> 4) * 8 + j;   // < 128 always
        Wf1[idx] = f2bf(ldin(w1, (o * 130 + cp) * 27 + tap, f));
    } else if (idx < N1 + N1E) {
        int i2 = idx - N1;
        int frag = i2 >> 9;            // kc*4 + nt (kc<2)
        int r    = i2 & 511;
        int lane = r >> 3, j = r & 7;
        int nt = frag & 3, kc = frag >> 2;
        int o   = nt * 16 + (lane & 15);
        int kap = kc * 32 + (lane >> 4) * 8 + j;  // kappa = tap*2 + ch
        unsigned short val = 0;
        if (kap < 54) {
            int tap = kap >> 1, ch = 128 + (kap & 1);
            val = f2bf(ldin(w1, (o * 130 + ch) * 27 + tap, f));
        }
        Wf1[idx] = val;                // Wf1e contiguous after Wf1
    } else if (idx < N1 + N1E + N2) {
        int i2 = idx - N1 - N1E;
        int frag = i2 >> 9;            // (tap*2 + kc)*4 + nt
        int r    = i2 & 511;
        int lane = r >> 3, j = r & 7;
        int nt = frag & 3;
        int tk = frag >> 2;
        int tap = tk >> 1, kc = tk & 1;
        int o = nt * 16 + (lane & 15);
        int c = kc * 32 + (lane >> 4) * 8 + j;
        Wf2[i2] = f2bf(ldin(w2, (o * 64 + c) * 27 + tap, f));
    } else if (idx < N1 + N1E + N2 + 256) {
        int j = idx - N1 - N1E - N2;
        const void* bp = (j < 64) ? bsv : (j < 128) ? btv : (j < 192) ? b1v : b2v;
        fbias[j] = ldin(bp, j & 63, f);
    }
}

// ---------------------------------------------------------------------------
// Projection (1x1x1 conv 32->64) + L2 normalize over channels.
// ---------------------------------------------------------------------------
__global__ __launch_bounds__(256) void proj_kernel(
        const void* __restrict__ Xsrc, const void* __restrict__ Xtgt,
        const void* __restrict__ Wsrc, const void* __restrict__ Wtgt,
        const float* __restrict__ fbias, const int* __restrict__ flag,
        unsigned short* __restrict__ SP, unsigned short* __restrict__ TP) {
    const int f = *flag;
    const void* Xin = blockIdx.y ? Xtgt : Xsrc;
    const void* W   = blockIdx.y ? Wtgt : Wsrc;
    const float* Bb = fbias + (blockIdx.y ? 64 : 0);
    unsigned short* Outp = blockIdx.y ? TP : SP;

    __shared__ float ws[2048];   // [ci][o]
    const int t = threadIdx.x;
    for (int i = t; i < 2048; i += 256) {
        int ci = i >> 6, o = i & 63;
        ws[i] = ldin(W, o * 32 + ci, f);
    }
    __syncthreads();

    const size_t v = (size_t)blockIdx.x * 256 + t;
    float acc[64];
#pragma unroll
    for (int o = 0; o < 64; ++o) acc[o] = Bb[o];
    if (f) {
        const float* Xf = (const float*)Xin;
        for (int ci = 0; ci < 32; ++ci) {
            float x = Xf[(size_t)ci * NVOX + v];
            const float4* wr = (const float4*)(ws + ci * 64);
#pragma unroll
            for (int o4 = 0; o4 < 16; ++o4) {
                float4 w4 = wr[o4];
                acc[o4 * 4 + 0] = fmaf(w4.x, x, acc[o4 * 4 + 0]);
                acc[o4 * 4 + 1] = fmaf(w4.y, x, acc[o4 * 4 + 1]);
                acc[o4 * 4 + 2] = fmaf(w4.z, x, acc[o4 * 4 + 2]);
                acc[o4 * 4 + 3] = fmaf(w4.w, x, acc[o4 * 4 + 3]);
            }
        }
    } else {
        const unsigned short* Xb = (const unsigned short*)Xin;
        for (int ci = 0; ci < 32; ++ci) {
            float x = bf2f(Xb[(size_t)ci * NVOX + v]);
            const float4* wr = (const float4*)(ws + ci * 64);
#pragma unroll
            for (int o4 = 0; o4 < 16; ++o4) {
                float4 w4 = wr[o4];
                acc[o4 * 4 + 0] = fmaf(w4.x, x, acc[o4 * 4 + 0]);
                acc[o4 * 4 + 1] = fmaf(w4.y, x, acc[o4 * 4 + 1]);
                acc[o4 * 4 + 2] = fmaf(w4.z, x, acc[o4 * 4 + 2]);
                acc[o4 * 4 + 3] = fmaf(w4.w, x, acc[o4 * 4 + 3]);
            }
        }
    }
    float s = 0.f;
#pragma unroll
    for (int o = 0; o < 64; ++o) s = fmaf(acc[o], acc[o], s);
    float scale = 1.f / fmaxf(sqrtf(s), 1e-12f);

    unsigned int pk[32];
#pragma unroll
    for (int o = 0; o < 32; ++o)
        pk[o] = (unsigned int)f2bf(acc[2 * o] * scale) |
                ((unsigned int)f2bf(acc[2 * o + 1] * scale) << 16);
    uint4* outp = (uint4*)(Outp + v * 64);
#pragma unroll
    for (int j = 0; j < 8; ++j)
        outp[j] = make_uint4(pk[4 * j], pk[4 * j + 1], pk[4 * j + 2], pk[4 * j + 3]);
}

// ---------------------------------------------------------------------------
// Correlation via MFMA (banded implicit GEMM) + exact fp32 online softmax.
// ---------------------------------------------------------------------------
DEV void tp_load(const unsigned short* __restrict__ TP, int t, int z, int y,
                 int it, uint4* pre) {
    const int zc = min(max(z + it / 5 - 2, 0), 63);
    const int yc = min(max(y + it % 5 - 2, 0), 63);
    const unsigned short* tbase = TP + ((size_t)zc * 64 + yc) * 4096;
#pragma unroll
    for (int j = 0; j < 3; ++j) {
        int i = t + j * 256;
        uint4 vv = make_uint4(0u, 0u, 0u, 0u);
        if (i < 640) {
            int pp = i >> 3, cc = i & 7;
            int xc = min(max(pp - 2, 0), 63);
            vv = *(const uint4*)(tbase + xc * 64 + cc * 8);
        }
        pre[j] = vv;
    }
}

DEV void tp_commit(unsigned short* buf, int t, const uint4* pre) {
#pragma unroll
    for (int j = 0; j < 3; ++j) {
        int i = t + j * 256;
        if (i < 640) {
            int pp = i >> 3, cc = i & 7;
            *(uint4*)((char*)buf + pp * 128 + ((cc ^ (pp & 7)) * 16)) = pre[j];
        }
    }
}

__global__ __launch_bounds__(256) void corr_kernel(
        const unsigned short* __restrict__ SP, const unsigned short* __restrict__ TP,
        unsigned short* __restrict__ X1, float* __restrict__ Out) {
    __shared__ __align__(16) unsigned short spb[64 * 64];      //  8192 B (swizzled)
    __shared__ __align__(16) unsigned short tpb[2][80 * 64];   // 20480 B (swizzled)
    __shared__ __align__(16) unsigned short stage[64 * 168];   // 21504 B
    __shared__ __align__(16) float band[64 * 5];               //  1280 B

    const int t = threadIdx.x;
    const int wv = t >> 6, lane = t & 63;
    const int q = lane >> 4, l16 = lane & 15;
    const int x0 = wv * 16;

    // XCD-aware bijective swizzle: XCD k gets z-slices [8k, 8k+8)
    const int bid = blockIdx.x;
    const int wg = (bid & 7) * 512 + (bid >> 3);
    const int z = wg >> 6, y = wg & 63;
    const size_t vbase = ((size_t)z * 64 + y) * 64;

    // --- SP row load (512 x 16B chunks, 2/thread) ---
    uint4 spv0, spv1;
    {
        int i0 = t, i1 = t + 256;
        spv0 = *(const uint4*)(SP + (vbase + (i0 >> 3)) * 64 + (i0 & 7) * 8);
        spv1 = *(const uint4*)(SP + (vbase + (i1 >> 3)) * 64 + (i1 & 7) * 8);
    }
    // zero stage padding cols [128,160)
    {
        int vox = t >> 2, c4 = t & 3;
        *(uint4*)(&stage[vox * 168 + 128 + c4 * 8]) = make_uint4(0u, 0u, 0u, 0u);
    }
    // commit SP to LDS (swizzled)
    {
        int i0 = t, i1 = t + 256;
        int xa = i0 >> 3, ca = i0 & 7;
        int xb = i1 >> 3, cb = i1 & 7;
        *(uint4*)((char*)spb + xa * 128 + ((ca ^ (xa & 7)) * 16)) = spv0;
        *(uint4*)((char*)spb + xb * 128 + ((cb ^ (xb & 7)) * 16)) = spv1;
    }

    // online softmax state (valid for t<64, voxel = t)
    float m = -1e30f, s2 = -1e30f, Zs = 0.f, S1 = 0.f, Ox = 0.f, Oy = 0.f, Oz = 0.f;

    uint4 pre[3];
    tp_load(TP, t, z, y, 0, pre);
    int p = 0;
    for (int it = 0; it < 25; ++it) {
        tp_commit(tpb[p], t, pre);
        __syncthreads();                         // barrier A
        if (it < 24) tp_load(TP, t, z, y, it + 1, pre);

        f32x4 acc[2] = {{0.f, 0.f, 0.f, 0.f}, {0.f, 0.f, 0.f, 0.f}};
        {
            const char* sb = (const char*)spb;
            const char* tb = (const char*)tpb[p];
            const int xr = x0 + l16;
#pragma unroll
            for (int kc = 0; kc < 2; ++kc) {
                bf16x8 a = *(const bf16x8*)(sb + xr * 128 + (((kc * 4 + q) ^ (xr & 7)) * 16));
#pragma unroll
                for (int nt = 0; nt < 2; ++nt) {
                    const int pr = x0 + nt * 16 + l16;
                    bf16x8 b = *(const bf16x8*)(tb + pr * 128 + (((kc * 4 + q) ^ (pr & 7)) * 16));
                    acc[nt] = __builtin_amdgcn_mfma_f32_16x16x32_bf16(a, b, acc[nt], 0, 0, 0);
                }
            }
        }
        // band extraction: C row (m) = q*4+r, col (n) = l16; dx = nt*16+l16-2-(q*4+r)
        const int kb = it * 5;
#pragma unroll
        for (int nt = 0; nt < 2; ++nt) {
#pragma unroll
            for (int r = 0; r < 4; ++r) {
                int ml = q * 4 + r;
                int dxp = nt * 16 + l16 - ml;     // dx + 2
                if ((unsigned)dxp < 5u) {
                    int xl = x0 + ml;
                    float d = acc[nt][r];
                    band[xl * 5 + dxp] = d;
                    stage[xl * 168 + kb + dxp] = f2bf(d);
                }
            }
        }
        __syncthreads();                         // barrier B
        if (t < 64) {
            const float fz = (float)(it / 5 - 2), fy = (float)(it % 5 - 2);
#pragma unroll
            for (int dxp = 0; dxp < 5; ++dxp) {
                float d = band[t * 5 + dxp];
                float fx = (float)(dxp - 2);
                if (d > m) {
                    float sc = __expf(m - d);
                    Zs = fmaf(Zs, sc, 1.f); S1 = fmaf(S1, sc, d);
                    Ox = fmaf(Ox, sc, fx); Oy = fmaf(Oy, sc, fy); Oz = fmaf(Oz, sc, fz);
                    s2 = m; m = d;
                } else {
                    float e = __expf(d - m);
                    Zs += e; S1 = fmaf(e, d, S1);
                    Ox = fmaf(e, fx, Ox); Oy = fmaf(e, fy, Oy); Oz = fmaf(e, fz, Oz);
                    s2 = fmaxf(s2, d);
                }
            }
        }
        p ^= 1;
    }

    if (t < 64) {
        float inv  = 1.f / fmaxf(Zs, 1e-8f);
        float eoz = Oz * inv, eoy = Oy * inv, eox = Ox * inv;
        float conf = fminf(inv, 1.f);
        float marg = fmaxf(conf - __expf(s2 - m) * inv, 0.f);
        float ent  = m + __logf(fmaxf(Zs, 1e-8f)) - S1 * inv;
        stage[t * 168 + 125] = f2bf(eoz);
        stage[t * 168 + 126] = f2bf(eoy);
        stage[t * 168 + 127] = f2bf(eox);
        stage[t * 168 + 128] = f2bf(conf);
        stage[t * 168 + 129] = f2bf(ent);
        const size_t v = vbase + t;
        Out[v]                    = eoz;
        Out[(size_t)NVOX + v]     = eoy;
        Out[(size_t)2 * NVOX + v] = eox;
        Out[(size_t)3 * NVOX + v] = conf;
        Out[(size_t)4 * NVOX + v] = marg;
        Out[(size_t)5 * NVOX + v] = ent;
    }
    __syncthreads();

    // X1 assembly: 64 vox x 20 uint4
#pragma unroll
    for (int j = 0; j < 5; ++j) {
        int i = t + j * 256;
        int vox = i / 20, cc = i % 20;
        *(uint4*)(X1 + (vbase + vox) * 160 + (size_t)cc * 8) =
            *(const uint4*)(&stage[vox * 168 + cc * 8]);
    }
}

// ---------------------------------------------------------------------------
// 3x3x3 conv, implicit GEMM via mfma_f32_16x16x32_bf16, zero padding.
// Block = one (z,y) x-row: 64 voxels x 64 out-ch. Hybrid 2x2 wave tiling,
// double-buffered staging, one barrier per (dz,dy) iteration.
// TAIL: conv1 stages only ch 0..127 (exact 4 K-chunks); ch 128..129 (conf,
// ent) are handled by a small im2col GEMM (K=54 pad 64) done once per block
// before the main loop, using rowbuf[1] as scratch (first commit targets
// rowbuf[0], so no overlap hazard). Cuts MFMA count 18.5% and staging 20%,
// and LDS 44.5->35.9 KB => 4 blocks/CU.
// ---------------------------------------------------------------------------
template <int XSTRIDE, int CPAD, int LSTRIDE, int KC, int NLD, bool TAIL>
__global__ __launch_bounds__(256) void conv3_kernel(
        const unsigned short* __restrict__ Xin, const unsigned short* __restrict__ Wf,
        const unsigned short* __restrict__ Wfe,
        const float* __restrict__ Bias, unsigned short* __restrict__ Out) {
    __shared__ unsigned short rowbuf[2][66 * LSTRIDE];
    const int lin = blockIdx.x;
    const int z = (lin & 7) * 8 + ((lin >> 3) >> 6);
    const int y = (lin >> 3) & 63;
    const int t = threadIdx.x;
    const int wv = t >> 6, lane = t & 63;
    const int quad = lane >> 4, l16 = lane & 15;
    const int mt2 = (wv & 1) * 2;    // m-tile pair base
    const int nt2 = (wv >> 1) * 2;   // n-tile pair base
    const int CH16 = CPAD / 8;

    f32x4 acc[2][2] = {{{0.f,0.f,0.f,0.f},{0.f,0.f,0.f,0.f}},
                       {{0.f,0.f,0.f,0.f},{0.f,0.f,0.f,0.f}}};

    uint4 pre[NLD];
    // prologue: loads for iteration 0 (dz=-1, dy=-1) -- issue before TAIL work
    {
        const int zz = z - 1, yy = y - 1;
        const bool valid = (unsigned)zz < 64u && (unsigned)yy < 64u;
        const unsigned short* base = Xin + (((size_t)(valid ? zz : 0) * 64 + (valid ? yy : 0)) * 64) * XSTRIDE;
#pragma unroll
        for (int i = 0; i < NLD; ++i) {
            int idx = t + i * 256;
            uint4 val = make_uint4(0u, 0u, 0u, 0u);
            if (idx < 66 * CH16) {
                int xi = idx / CH16, ci = idx % CH16;
                int gx = xi - 1;
                if (valid && gx >= 0 && gx < 64) val = *(const uint4*)(base + gx * XSTRIDE + ci * 8);
            }
            pre[i] = val;
        }
    }

    if (TAIL) {
        // im2col gather of ch 128/129 neighborhoods into rowbuf[1]:
        // ebuf[vox][kappa], kappa = tap*2 + ch, row stride 72 shorts.
        unsigned short* ebuf = &rowbuf[1][0];
#pragma unroll
        for (int i2 = 0; i2 < 8; ++i2) {
            int i = t + i2 * 256;                 // 0..2047
            int vox = i >> 5, slot = i & 31;
            unsigned int val = 0u;
            int kap;
            if (slot < 27) {
                int dz = slot / 9 - 1, dy = (slot / 3) % 3 - 1, dxx = slot % 3 - 1;
                int zz = z + dz, yy = y + dy, xx = vox + dxx;
                kap = slot * 2;
                if ((unsigned)zz < 64u && (unsigned)yy < 64u && (unsigned)xx < 64u)
                    val = *(const unsigned int*)(Xin + (((size_t)zz * 64 + yy) * 64 + xx) * XSTRIDE + 128);
            } else {
                kap = 54 + (slot - 27) * 2;       // zero-fill kappa 54..63
            }
            *(unsigned int*)(ebuf + vox * 72 + kap) = val;
        }
        __syncthreads();
#pragma unroll
        for (int kc = 0; kc < 2; ++kc) {
            bf16x8 bte[2];
#pragma unroll
            for (int nl = 0; nl < 2; ++nl)
                bte[nl] = *(const bf16x8*)(Wfe + (size_t)(kc * 4 + nt2 + nl) * 512 + lane * 8);
#pragma unroll
            for (int ml = 0; ml < 2; ++ml) {
                bf16x8 a = *(const bf16x8*)(ebuf + ((mt2 + ml) * 16 + l16) * 72 + (kc * 4 + quad) * 8);
#pragma unroll
                for (int nl = 0; nl < 2; ++nl)
                    acc[ml][nl] = __builtin_amdgcn_mfma_f32_16x16x32_bf16(a, bte[nl], acc[ml][nl], 0, 0, 0);
            }
        }
        __syncthreads();   // ds_reads drained; rowbuf[1] safe to reuse at it=1
    }

    int p = 0;
    for (int it = 0; it < 9; ++it) {
        // commit prefetched rows into LDS buffer p
#pragma unroll
        for (int i = 0; i < NLD; ++i) {
            int idx = t + i * 256;
            if (idx < 66 * CH16) {
                int xi = idx / CH16, ci = idx % CH16;
                *(uint4*)(&rowbuf[p][xi * LSTRIDE + ci * 8]) = pre[i];
            }
        }
        __syncthreads();
        // issue next iteration's loads (overlaps the MFMA work below)
        if (it < 8) {
            const int itn = it + 1;
            const int zz = z + itn / 3 - 1, yy = y + itn % 3 - 1;
            const bool valid = (unsigned)zz < 64u && (unsigned)yy < 64u;
            const unsigned short* base = Xin + (((size_t)(valid ? zz : 0) * 64 + (valid ? yy : 0)) * 64) * XSTRIDE;
#pragma unroll
            for (int i = 0; i < NLD; ++i) {
                int idx = t + i * 256;
                uint4 val = make_uint4(0u, 0u, 0u, 0u);
                if (idx < 66 * CH16) {
                    int xi = idx / CH16, ci = idx % CH16;
                    int gx = xi - 1;
                    if (valid && gx >= 0 && gx < 64) val = *(const uint4*)(base + gx * XSTRIDE + ci * 8);
                }
                pre[i] = val;
            }
        }
        const unsigned short* rp = rowbuf[p];
#pragma unroll
        for (int dx = 0; dx < 3; ++dx) {
            const int tap = it * 3 + dx;
            const unsigned short* wt = Wf + ((size_t)tap * KC * 4) * 512 + lane * 8;
            bf16x8 bf[KC][2];
#pragma unroll
            for (int kc = 0; kc < KC; ++kc)
#pragma unroll
                for (int nl = 0; nl < 2; ++nl)
                    bf[kc][nl] = *(const bf16x8*)(wt + (size_t)(kc * 4 + nt2 + nl) * 512);
#pragma unroll
            for (int kc = 0; kc < KC; ++kc) {
#pragma unroll
                for (int ml = 0; ml < 2; ++ml) {
                    bf16x8 a = *(const bf16x8*)(&rp[((mt2 + ml) * 16 + l16 + dx) * LSTRIDE + kc * 32 + quad * 8]);
#pragma unroll
                    for (int nl = 0; nl < 2; ++nl)
                        acc[ml][nl] = __builtin_amdgcn_mfma_f32_16x16x32_bf16(a, bf[kc][nl], acc[ml][nl], 0, 0, 0);
                }
            }
        }
        p ^= 1;
    }

    const size_t vbase = ((size_t)z * 64 + y) * 64;
#pragma unroll
    for (int ml = 0; ml < 2; ++ml) {
#pragma unroll
        for (int nl = 0; nl < 2; ++nl) {
            const int oc = (nt2 + nl) * 16 + l16;
            const float bv = Bias[oc];
#pragma unroll
            for (int r = 0; r < 4; ++r)
                Out[(vbase + (mt2 + ml) * 16 + quad * 4 + r) * 64 + oc] = f2bf(acc[ml][nl][r] + bv);
        }
    }
}

// ---------------------------------------------------------------------------
// Per-channel sum / sumsq over all voxels (InstanceNorm stats).
// ---------------------------------------------------------------------------
__global__ __launch_bounds__(256) void stats_kernel(
        const unsigned short* __restrict__ H, float* __restrict__ stats) {
    const int t = threadIdx.x;
    const int c = t & 63, g = t >> 6;
    float s = 0.f, q = 0.f;
    for (int v = blockIdx.x * 4 + g; v < NVOX; v += gridDim.x * 4) {
        float x = bf2f(H[(size_t)v * 64 + c]);
        s += x; q = fmaf(x, x, q);
    }
    __shared__ float ls[256], lq[256];
    ls[t] = s; lq[t] = q;
    __syncthreads();
    if (t < 64) {
        s = ls[t] + ls[t + 64] + ls[t + 128] + ls[t + 192];
        q = lq[t] + lq[t + 64] + lq[t + 128] + lq[t + 192];
        atomicAdd(&stats[c], s);
        atomicAdd(&stats[64 + c], q);
    }
}

__global__ void finalize_kernel(const float* __restrict__ stats, float* __restrict__ musr) {
    int c = threadIdx.x;
    if (c < 64) {
        float mu  = stats[c] * (1.0f / 262144.0f);
        float var = stats[64 + c] * (1.0f / 262144.0f) - mu * mu;
        musr[c] = mu;
        musr[64 + c] = rsqrtf(var + 1e-5f);
    }
}

// ---------------------------------------------------------------------------
// Elementwise InstanceNorm + exact GELU, [v][64] -> [v][64] bf16
// ---------------------------------------------------------------------------
__global__ __launch_bounds__(256) void norm_gelu_kernel(
        const unsigned short* __restrict__ H, const float* __restrict__ musr,
        unsigned short* __restrict__ G) {
    const size_t base = ((size_t)blockIdx.x * 256 + threadIdx.x) * 8;
    uint4 u = *(const uint4*)(H + base);
    const int c0 = (int)(base & 63);
    const unsigned int uu[4] = {u.x, u.y, u.z, u.w};
    unsigned int w[4];
#pragma unroll
    for (int p = 0; p < 4; ++p) {
        int c = c0 + p * 2;
        float x0 = (bflo(uu[p]) - musr[c]) * musr[64 + c];
        float x1 = (bfhi(uu[p]) - musr[c + 1]) * musr[64 + c + 1];
        float g0 = 0.5f * x0 * (1.f + erff(x0 * 0.70710678118f));
        float g1 = 0.5f * x1 * (1.f + erff(x1 * 0.70710678118f));
        w[p] = (unsigned int)f2bf(g0) | ((unsigned int)f2bf(g1) << 16);
    }
    *(uint4*)(G + base) = make_uint4(w[0], w[1], w[2], w[3]);
}

// ---------------------------------------------------------------------------
// Final: InstanceNorm + exact GELU on h2, write fp32 channel planes [64][v].
// ---------------------------------------------------------------------------
__global__ __launch_bounds__(256) void out_final_kernel(
        const unsigned short* __restrict__ H2, const float* __restrict__ musr,
        float* __restrict__ OutEnc) {
    __shared__ float tile[64 * 260];
    const int t = threadIdx.x;
    const size_t v0 = (size_t)blockIdx.x * 256;
#pragma unroll
    for (int i = 0; i < 8; ++i) {
        int chunk = t + i * 256;                  // 0..2047
        uint4 u = *(const uint4*)(H2 + v0 * 64 + (size_t)chunk * 8);
        int vox = chunk >> 3;
        int c0 = (chunk & 7) * 8;
        const unsigned int uu[4] = {u.x, u.y, u.z, u.w};
#pragma unroll
        for (int p = 0; p < 4; ++p) {
            int c = c0 + p * 2;
            float x0 = (bflo(uu[p]) - musr[c]) * musr[64 + c];
            float x1 = (bfhi(uu[p]) - musr[c + 1]) * musr[64 + c + 1];
            tile[c * 260 + vox]       = 0.5f * x0 * (1.f + erff(x0 * 0.70710678118f));
            tile[(c + 1) * 260 + vox] = 0.5f * x1 * (1.f + erff(x1 * 0.70710678118f));
        }
    }
    __syncthreads();
    const int c = t >> 2, sub = t & 3;
#pragma unroll
    for (int iter = 0; iter < 16; ++iter) {
        int fq = iter * 4 + sub;                  // float4 index 0..63
        float4 val = *(const float4*)(&tile[c * 260 + fq * 4]);
        *(float4*)(OutEnc + (size_t)c * NVOX + v0 + fq * 4) = val;
    }
}

// ---------------------------------------------------------------------------
extern "C" void kernel_launch(void* const* d_in, const int* in_sizes, int n_in,
                              void* d_out, int out_size, void* d_ws, size_t ws_size,
                              hipStream_t stream) {
    const void* src  = d_in[0];
    const void* tgt  = d_in[1];
    const void* wsrc = d_in[2];
    const void* bsrc = d_in[3];
    const void* wtgt = d_in[4];
    const void* btgt = d_in[5];
    const void* w1   = d_in[6];
    const void* b1   = d_in[7];
    const void* w2   = d_in[8];
    const void* b2   = d_in[9];
    float* out = (float*)d_out;   // fp32 outputs, 70*262144 elements

    char* ws = (char*)d_ws;
    unsigned short* TPb = (unsigned short*)(ws);                  // 33,554,432 B
    unsigned short* SPb = (unsigned short*)(ws + 33554432);       // 33,554,432 B
    unsigned short* X1  = (unsigned short*)(ws + 67108864);       // 83,886,080 B
    unsigned short* Wf1 = (unsigned short*)(ws + 150994944);      // main+tail frags
    unsigned short* Wf2 = (unsigned short*)(ws + 151547904);      //    221,184 B
    int*   flag   = (int*)  (ws + 151769088);
    float* fbias  = (float*)(ws + 151769152);                     // 256 f32
    float* stats1 = (float*)(ws + 151770176);                     // 128 f32
    float* musr1  = (float*)(ws + 151770688);
    float* stats2 = (float*)(ws + 151771200);
    float* musr2  = (float*)(ws + 151771712);
    unsigned short* H1 = SPb;
    unsigned short* G1 = TPb;
    unsigned short* H2 = X1;
    unsigned short* Wf1e = Wf1 + 27 * 4 * 4 * 512;                // tail frags

    (void)hipMemsetAsync(stats1, 0, 2048, stream);
    sniff_kernel<<<1, 256, 0, stream>>>((const unsigned short*)src, flag);
    prep_kernel<<<1313, 256, 0, stream>>>(w1, w2, bsrc, btgt, b1, b2, flag, Wf1, Wf2, fbias);
    proj_kernel<<<dim3(1024, 2), 256, 0, stream>>>(src, tgt, wsrc, wtgt, fbias, flag, SPb, TPb);
    corr_kernel<<<4096, 256, 0, stream>>>(SPb, TPb, X1, out);
    conv3_kernel<160, 128, 136, 4, 5, true><<<4096, 256, 0, stream>>>(X1, Wf1, Wf1e, fbias + 128, H1);
    stats_kernel<<<256, 256, 0, stream>>>(H1, stats1);
    finalize_kernel<<<1, 64, 0, stream>>>(stats1, musr1);
    norm_gelu_kernel<<<8192, 256, 0, stream>>>(H1, musr1, G1);
    conv3_kernel<64, 64, 72, 2, 3, false><<<4096, 256, 0, stream>>>(G1, Wf2, nullptr, fbias + 192, H2);
    stats_kernel<<<256, 256, 0, stream>>>(H2, stats2);
    finalize_kernel<<<1, 64, 0, stream>>>(stats2, musr2);
    out_final_kernel<<<1024, 256, 0, stream>>>(H2, musr2, out + 6 * (size_t)NVOX);
}

// Round 4
// 736.004 us; speedup vs baseline: 1.2471x; 1.0793x over previous
//
#include <hip/hip_runtime.h>

#define DEV __device__ __forceinline__

typedef short bf16x8 __attribute__((ext_vector_type(8)));
typedef float f32x4 __attribute__((ext_vector_type(4)));

static const int NVOX = 262144; // 64^3

DEV float bflo(unsigned int u) { return __uint_as_float(u << 16); }
DEV float bfhi(unsigned int u) { return __uint_as_float(u & 0xffff0000u); }
DEV float bf2f(unsigned short s) { return __uint_as_float(((unsigned int)s) << 16); }
DEV unsigned short f2bf(float f) {
    unsigned int x = __float_as_uint(f);
    x += 0x7fffu + ((x >> 16) & 1u);   // RNE
    return (unsigned short)(x >> 16);
}
// dual-dtype raw-input load: f==1 -> fp32, f==0 -> bf16
DEV float ldin(const void* p, int i, int f) {
    return f ? ((const float*)p)[i] : bf2f(((const unsigned short*)p)[i]);
}

// ---------------------------------------------------------------------------
// Dtype sniffer (insurance; fp32 inputs confirmed).
// ---------------------------------------------------------------------------
__global__ void sniff_kernel(const unsigned short* __restrict__ src, int* __restrict__ flag) {
    __shared__ int cnt[256];
    int t = threadIdx.x;
    int c = 0;
    for (int i = t; i < 4096; i += 256) {
        unsigned int u = (unsigned int)src[i] & 0x7fffu;
        c += (u >= 0x4900u) ? 1 : 0;
    }
    cnt[t] = c;
    __syncthreads();
    for (int s = 128; s > 0; s >>= 1) {
        if (t < s) cnt[t] += cnt[t + s];
        __syncthreads();
    }
    if (t == 0) *flag = (cnt[0] > 8) ? 1 : 0;
}

// ---------------------------------------------------------------------------
// Weight prep into MFMA B-fragment order:
//   Wf1: conv1 main K-chunks, ch 0..127:  [tap][kc<4][nt][lane][j], 512 sh/frag
//   Wf1e: conv1 tail (ch 128..129 x 27 taps -> K=54 pad 64): [kc<2][nt][lane][j]
//   Wf2: conv2, K=64: [tap][kc<2][nt][lane][j]
//   Fragment element (lane,j) = W[o = nt*16 + (lane&15)][k = kc*32 + (lane>>4)*8 + j]
// ---------------------------------------------------------------------------
__global__ void prep_kernel(const void* __restrict__ w1, const void* __restrict__ w2,
                            const void* __restrict__ bsv, const void* __restrict__ btv,
                            const void* __restrict__ b1v, const void* __restrict__ b2v,
                            const int* __restrict__ flag,
                            unsigned short* __restrict__ Wf1,
                            unsigned short* __restrict__ Wf2,
                            float* __restrict__ fbias) {
    const int f = *flag;
    int idx = blockIdx.x * 256 + threadIdx.x;
    const int N1  = 27 * 4 * 4 * 512;   // 221184 (main, kc<4)
    const int N1E = 2 * 4 * 512;        //   4096 (tail)
    const int N2  = 27 * 2 * 4 * 512;   // 110592
    if (idx < N1) {
        int frag = idx >> 9;           // (tap*4 + kc)*4 + nt
        int r    = idx & 511;
        int lane = r >> 3, j = r & 7;
        int nt = frag & 3;
        int tk = frag >> 2;            // tap*4 + kc
        int tap = tk >> 2, kc = tk & 3;
        int o  = nt * 16 + (lane & 15);
        int cp = kc * 32 + (lane >> 4) * 8 + j;   // < 128 always
        Wf1[idx] = f2bf(ldin(w1, (o * 130 + cp) * 27 + tap, f));
    } else if (idx < N1 + N1E) {
        int i2 = idx - N1;
        int frag = i2 >> 9;            // kc*4 + nt (kc<2)
        int r    = i2 & 511;
        int lane = r >> 3, j = r & 7;
        int nt = frag & 3, kc = frag >> 2;
        int o   = nt * 16 + (lane & 15);
        int kap = kc * 32 + (lane >> 4) * 8 + j;  // kappa = tap*2 + ch
        unsigned short val = 0;
        if (kap < 54) {
            int tap = kap >> 1, ch = 128 + (kap & 1);
            val = f2bf(ldin(w1, (o * 130 + ch) * 27 + tap, f));
        }
        Wf1[idx] = val;                // Wf1e contiguous after Wf1
    } else if (idx < N1 + N1E + N2) {
        int i2 = idx - N1 - N1E;
        int frag = i2 >> 9;            // (tap*2 + kc)*4 + nt
        int r    = i2 & 511;
        int lane = r >> 3, j = r & 7;
        int nt = frag & 3;
        int tk = frag >> 2;
        int tap = tk >> 1, kc = tk & 1;
        int o = nt * 16 + (lane & 15);
        int c = kc * 32 + (lane >> 4) * 8 + j;
        Wf2[i2] = f2bf(ldin(w2, (o * 64 + c) * 27 + tap, f));
    } else if (idx < N1 + N1E + N2 + 256) {
        int j = idx - N1 - N1E - N2;
        const void* bp = (j < 64) ? bsv : (j < 128) ? btv : (j < 192) ? b1v : b2v;
        fbias[j] = ldin(bp, j & 63, f);
    }
}

// ---------------------------------------------------------------------------
// Projection (1x1x1 conv 32->64) + L2 normalize over channels.
// ---------------------------------------------------------------------------
__global__ __launch_bounds__(256) void proj_kernel(
        const void* __restrict__ Xsrc, const void* __restrict__ Xtgt,
        const void* __restrict__ Wsrc, const void* __restrict__ Wtgt,
        const float* __restrict__ fbias, const int* __restrict__ flag,
        unsigned short* __restrict__ SP, unsigned short* __restrict__ TP) {
    const int f = *flag;
    const void* Xin = blockIdx.y ? Xtgt : Xsrc;
    const void* W   = blockIdx.y ? Wtgt : Wsrc;
    const float* Bb = fbias + (blockIdx.y ? 64 : 0);
    unsigned short* Outp = blockIdx.y ? TP : SP;

    __shared__ float ws[2048];   // [ci][o]
    const int t = threadIdx.x;
    for (int i = t; i < 2048; i += 256) {
        int ci = i >> 6, o = i & 63;
        ws[i] = ldin(W, o * 32 + ci, f);
    }
    __syncthreads();

    const size_t v = (size_t)blockIdx.x * 256 + t;
    float acc[64];
#pragma unroll
    for (int o = 0; o < 64; ++o) acc[o] = Bb[o];
    if (f) {
        const float* Xf = (const float*)Xin;
        for (int ci = 0; ci < 32; ++ci) {
            float x = Xf[(size_t)ci * NVOX + v];
            const float4* wr = (const float4*)(ws + ci * 64);
#pragma unroll
            for (int o4 = 0; o4 < 16; ++o4) {
                float4 w4 = wr[o4];
                acc[o4 * 4 + 0] = fmaf(w4.x, x, acc[o4 * 4 + 0]);
                acc[o4 * 4 + 1] = fmaf(w4.y, x, acc[o4 * 4 + 1]);
                acc[o4 * 4 + 2] = fmaf(w4.z, x, acc[o4 * 4 + 2]);
                acc[o4 * 4 + 3] = fmaf(w4.w, x, acc[o4 * 4 + 3]);
            }
        }
    } else {
        const unsigned short* Xb = (const unsigned short*)Xin;
        for (int ci = 0; ci < 32; ++ci) {
            float x = bf2f(Xb[(size_t)ci * NVOX + v]);
            const float4* wr = (const float4*)(ws + ci * 64);
#pragma unroll
            for (int o4 = 0; o4 < 16; ++o4) {
                float4 w4 = wr[o4];
                acc[o4 * 4 + 0] = fmaf(w4.x, x, acc[o4 * 4 + 0]);
                acc[o4 * 4 + 1] = fmaf(w4.y, x, acc[o4 * 4 + 1]);
                acc[o4 * 4 + 2] = fmaf(w4.z, x, acc[o4 * 4 + 2]);
                acc[o4 * 4 + 3] = fmaf(w4.w, x, acc[o4 * 4 + 3]);
            }
        }
    }
    float s = 0.f;
#pragma unroll
    for (int o = 0; o < 64; ++o) s = fmaf(acc[o], acc[o], s);
    float scale = 1.f / fmaxf(sqrtf(s), 1e-12f);

    unsigned int pk[32];
#pragma unroll
    for (int o = 0; o < 32; ++o)
        pk[o] = (unsigned int)f2bf(acc[2 * o] * scale) |
                ((unsigned int)f2bf(acc[2 * o + 1] * scale) << 16);
    uint4* outp = (uint4*)(Outp + v * 64);
#pragma unroll
    for (int j = 0; j < 8; ++j)
        outp[j] = make_uint4(pk[4 * j], pk[4 * j + 1], pk[4 * j + 2], pk[4 * j + 3]);
}

// ---------------------------------------------------------------------------
// Correlation via MFMA (banded implicit GEMM), ONE barrier per (dz,dy)
// iteration, bf16 corr into swizzled stage; deferred fully-parallel softmax
// tail (4 lanes per voxel) computes the 6 output planes + extras once per
// block. k>=125 slots of stage are NEVER read unguarded (0*NaN lesson).
// ---------------------------------------------------------------------------
DEV void tp_load(const unsigned short* __restrict__ TP, int t, int z, int y,
                 int it, uint4* pre) {
    const int zc = min(max(z + it / 5 - 2, 0), 63);
    const int yc = min(max(y + it % 5 - 2, 0), 63);
    const unsigned short* tbase = TP + ((size_t)zc * 64 + yc) * 4096;
#pragma unroll
    for (int j = 0; j < 3; ++j) {
        int i = t + j * 256;
        uint4 vv = make_uint4(0u, 0u, 0u, 0u);
        if (i < 640) {
            int pp = i >> 3, cc = i & 7;
            int xc = min(max(pp - 2, 0), 63);
            vv = *(const uint4*)(tbase + xc * 64 + cc * 8);
        }
        pre[j] = vv;
    }
}

DEV void tp_commit(unsigned short* buf, int t, const uint4* pre) {
#pragma unroll
    for (int j = 0; j < 3; ++j) {
        int i = t + j * 256;
        if (i < 640) {
            int pp = i >> 3, cc = i & 7;
            *(uint4*)((char*)buf + pp * 128 + ((cc ^ (pp & 7)) * 16)) = pre[j];
        }
    }
}

__global__ __launch_bounds__(256) void corr_kernel(
        const unsigned short* __restrict__ SP, const unsigned short* __restrict__ TP,
        unsigned short* __restrict__ X1, float* __restrict__ Out) {
    __shared__ __align__(16) unsigned short spb[64 * 64];      //  8192 B (swizzled)
    __shared__ __align__(16) unsigned short tpb[2][80 * 64];   // 20480 B (swizzled)
    __shared__ __align__(16) unsigned short stage[64 * 128];   // 16384 B (swizzled)

    const int t = threadIdx.x;
    const int wv = t >> 6, lane = t & 63;
    const int q = lane >> 4, l16 = lane & 15;
    const int x0 = wv * 16;

    // XCD-aware bijective swizzle: XCD k gets z-slices [8k, 8k+8)
    const int bid = blockIdx.x;
    const int wg = (bid & 7) * 512 + (bid >> 3);
    const int z = wg >> 6, y = wg & 63;
    const size_t vbase = ((size_t)z * 64 + y) * 64;

    // --- SP row load (512 x 16B chunks, 2/thread), commit swizzled ---
    {
        int i0 = t, i1 = t + 256;
        uint4 spv0 = *(const uint4*)(SP + (vbase + (i0 >> 3)) * 64 + (i0 & 7) * 8);
        uint4 spv1 = *(const uint4*)(SP + (vbase + (i1 >> 3)) * 64 + (i1 & 7) * 8);
        int xa = i0 >> 3, ca = i0 & 7;
        int xb = i1 >> 3, cb = i1 & 7;
        *(uint4*)((char*)spb + xa * 128 + ((ca ^ (xa & 7)) * 16)) = spv0;
        *(uint4*)((char*)spb + xb * 128 + ((cb ^ (xb & 7)) * 16)) = spv1;
    }

    uint4 pre[3];
    tp_load(TP, t, z, y, 0, pre);
    int p = 0;
    for (int it = 0; it < 25; ++it) {
        tp_commit(tpb[p], t, pre);
        __syncthreads();                         // single barrier per iteration
        if (it < 24) tp_load(TP, t, z, y, it + 1, pre);

        f32x4 acc[2] = {{0.f, 0.f, 0.f, 0.f}, {0.f, 0.f, 0.f, 0.f}};
        {
            const char* sb = (const char*)spb;
            const char* tb = (const char*)tpb[p];
            const int xr = x0 + l16;
#pragma unroll
            for (int kc = 0; kc < 2; ++kc) {
                bf16x8 a = *(const bf16x8*)(sb + xr * 128 + (((kc * 4 + q) ^ (xr & 7)) * 16));
#pragma unroll
                for (int nt = 0; nt < 2; ++nt) {
                    const int pr = x0 + nt * 16 + l16;
                    bf16x8 b = *(const bf16x8*)(tb + pr * 128 + (((kc * 4 + q) ^ (pr & 7)) * 16));
                    acc[nt] = __builtin_amdgcn_mfma_f32_16x16x32_bf16(a, b, acc[nt], 0, 0, 0);
                }
            }
        }
        // band extraction: C row (m) = q*4+r, col (n) = l16; dxp = nt*16+l16-(q*4+r)
        const int kb = it * 5;
        char* sg = (char*)stage;
#pragma unroll
        for (int nt = 0; nt < 2; ++nt) {
#pragma unroll
            for (int r = 0; r < 4; ++r) {
                int ml = q * 4 + r;
                int dxp = nt * 16 + l16 - ml;     // dx + 2
                if ((unsigned)dxp < 5u) {
                    int xl = x0 + ml;
                    *(unsigned short*)(sg + xl * 256 + (((kb + dxp) * 2) ^ ((xl & 7) << 4))) =
                        f2bf(acc[nt][r]);
                }
            }
        }
        p ^= 1;
    }

    // ---- deferred softmax tail: 4 lanes per voxel, all 256 threads ----
    __syncthreads();
    {
        const int vox = t >> 2, part = t & 3;
        const int sx = (vox & 7) << 4;
        const char* sg = (const char*)stage;
        uint4 u[4];
#pragma unroll
        for (int j = 0; j < 4; ++j)
            u[j] = *(const uint4*)(sg + vox * 256 + ((part * 64 + j * 16) ^ sx));

        // pass 1: branchless top-2 over this lane's 32 values
        float m = -1e30f, s2 = -1e30f;
#pragma unroll
        for (int j = 0; j < 4; ++j) {
            const unsigned int uu[4] = {u[j].x, u[j].y, u[j].z, u[j].w};
#pragma unroll
            for (int w = 0; w < 4; ++w) {
                int k = part * 32 + j * 8 + w * 2;
                float d0 = (k < 125) ? bflo(uu[w]) : -1e30f;
                float d1 = (k + 1 < 125) ? bfhi(uu[w]) : -1e30f;
                float lo0 = fminf(d0, m); m = fmaxf(d0, m); s2 = fmaxf(s2, lo0);
                float lo1 = fminf(d1, m); m = fmaxf(d1, m); s2 = fmaxf(s2, lo1);
            }
        }
        // merge top-2 across the voxel's 4 lanes
#pragma unroll
        for (int off = 1; off <= 2; off <<= 1) {
            float om = __shfl_xor(m, off, 64);
            float os = __shfl_xor(s2, off, 64);
            float lo = fminf(m, om);
            m = fmaxf(m, om);
            s2 = fmaxf(fmaxf(s2, os), lo);
        }
        // pass 2: exp sums with incremental (dx,dy,dz)
        int kk = part * 32;
        int dz0 = kk / 25, rem = kk - dz0 * 25, dy0 = rem / 5, dx0 = rem - dy0 * 5;
        float fx = (float)(dx0 - 2), fy = (float)(dy0 - 2), fz = (float)(dz0 - 2);
        float Zs = 0.f, S1 = 0.f, Ox = 0.f, Oy = 0.f, Oz = 0.f;
#pragma unroll
        for (int j = 0; j < 4; ++j) {
            const unsigned int uu[4] = {u[j].x, u[j].y, u[j].z, u[j].w};
#pragma unroll
            for (int w = 0; w < 8; ++w) {
                int k = part * 32 + j * 8 + w;
                bool ok = (k < 125);
                float d = (w & 1) ? bfhi(uu[w >> 1]) : bflo(uu[w >> 1]);
                d = ok ? d : 0.f;                 // sanitize: garbage slot may be NaN
                float e = ok ? __expf(d - m) : 0.f;
                Zs += e; S1 = fmaf(e, d, S1);
                Ox = fmaf(e, fx, Ox); Oy = fmaf(e, fy, Oy); Oz = fmaf(e, fz, Oz);
                fx += 1.f;
                if (fx > 2.5f) { fx = -2.f; fy += 1.f; if (fy > 2.5f) { fy = -2.f; fz += 1.f; } }
            }
        }
        // quad reduce the 5 sums
#pragma unroll
        for (int off = 1; off <= 2; off <<= 1) {
            Zs += __shfl_xor(Zs, off, 64);
            S1 += __shfl_xor(S1, off, 64);
            Ox += __shfl_xor(Ox, off, 64);
            Oy += __shfl_xor(Oy, off, 64);
            Oz += __shfl_xor(Oz, off, 64);
        }
        if (part == 0) {
            float inv  = 1.f / fmaxf(Zs, 1e-8f);
            float eoz = Oz * inv, eoy = Oy * inv, eox = Ox * inv;
            float conf = fminf(inv, 1.f);
            float marg = fmaxf(conf - __expf(s2 - m) * inv, 0.f);
            float ent  = m + __logf(fmaxf(Zs, 1e-8f)) - S1 * inv;
            char* sgw = (char*)stage;
            *(unsigned short*)(sgw + vox * 256 + (250 ^ sx)) = f2bf(eoz);
            *(unsigned short*)(sgw + vox * 256 + (252 ^ sx)) = f2bf(eoy);
            *(unsigned short*)(sgw + vox * 256 + (254 ^ sx)) = f2bf(eox);
            const size_t v = vbase + vox;
            *(unsigned int*)(X1 + v * 160 + 128) =
                (unsigned int)f2bf(conf) | ((unsigned int)f2bf(ent) << 16);
            Out[v]                    = eoz;
            Out[(size_t)NVOX + v]     = eoy;
            Out[(size_t)2 * NVOX + v] = eox;
            Out[(size_t)3 * NVOX + v] = conf;
            Out[(size_t)4 * NVOX + v] = marg;
            Out[(size_t)5 * NVOX + v] = ent;
        }
    }
    __syncthreads();

    // X1 flush: ch 0..127 (corr + offsets), 64 vox x 16 uint4
#pragma unroll
    for (int j = 0; j < 4; ++j) {
        int i = t + j * 256;
        int vox = i >> 4, cc = i & 15;
        *(uint4*)(X1 + (vbase + vox) * 160 + (size_t)cc * 8) =
            *(const uint4*)((const char*)stage + vox * 256 + ((cc * 16) ^ ((vox & 7) << 4)));
    }
}

// ---------------------------------------------------------------------------
// 3x3x3 conv, implicit GEMM via mfma_f32_16x16x32_bf16, zero padding.
// Block = one (z,y) x-row: 64 voxels x 64 out-ch. Hybrid 2x2 wave tiling,
// double-buffered staging, one barrier per (dz,dy) iteration.
// TAIL: conv1 stages only ch 0..127 (exact 4 K-chunks); ch 128..129 (conf,
// ent) are handled by a small im2col GEMM (K=54 pad 64) done once per block
// before the main loop, using rowbuf[1] as scratch.
// ---------------------------------------------------------------------------
template <int XSTRIDE, int CPAD, int LSTRIDE, int KC, int NLD, bool TAIL>
__global__ __launch_bounds__(256) void conv3_kernel(
        const unsigned short* __restrict__ Xin, const unsigned short* __restrict__ Wf,
        const unsigned short* __restrict__ Wfe,
        const float* __restrict__ Bias, unsigned short* __restrict__ Out) {
    __shared__ unsigned short rowbuf[2][66 * LSTRIDE];
    const int lin = blockIdx.x;
    const int z = (lin & 7) * 8 + ((lin >> 3) >> 6);
    const int y = (lin >> 3) & 63;
    const int t = threadIdx.x;
    const int wv = t >> 6, lane = t & 63;
    const int quad = lane >> 4, l16 = lane & 15;
    const int mt2 = (wv & 1) * 2;    // m-tile pair base
    const int nt2 = (wv >> 1) * 2;   // n-tile pair base
    const int CH16 = CPAD / 8;

    f32x4 acc[2][2] = {{{0.f,0.f,0.f,0.f},{0.f,0.f,0.f,0.f}},
                       {{0.f,0.f,0.f,0.f},{0.f,0.f,0.f,0.f}}};

    uint4 pre[NLD];
    // prologue: loads for iteration 0 (dz=-1, dy=-1) -- issue before TAIL work
    {
        const int zz = z - 1, yy = y - 1;
        const bool valid = (unsigned)zz < 64u && (unsigned)yy < 64u;
        const unsigned short* base = Xin + (((size_t)(valid ? zz : 0) * 64 + (valid ? yy : 0)) * 64) * XSTRIDE;
#pragma unroll
        for (int i = 0; i < NLD; ++i) {
            int idx = t + i * 256;
            uint4 val = make_uint4(0u, 0u, 0u, 0u);
            if (idx < 66 * CH16) {
                int xi = idx / CH16, ci = idx % CH16;
                int gx = xi - 1;
                if (valid && gx >= 0 && gx < 64) val = *(const uint4*)(base + gx * XSTRIDE + ci * 8);
            }
            pre[i] = val;
        }
    }

    if (TAIL) {
        // im2col gather of ch 128/129 neighborhoods into rowbuf[1]:
        // ebuf[vox][kappa], kappa = tap*2 + ch, row stride 72 shorts.
        unsigned short* ebuf = &rowbuf[1][0];
#pragma unroll
        for (int i2 = 0; i2 < 8; ++i2) {
            int i = t + i2 * 256;                 // 0..2047
            int vox = i >> 5, slot = i & 31;
            unsigned int val = 0u;
            int kap;
            if (slot < 27) {
                int dz = slot / 9 - 1, dy = (slot / 3) % 3 - 1, dxx = slot % 3 - 1;
                int zz = z + dz, yy = y + dy, xx = vox + dxx;
                kap = slot * 2;
                if ((unsigned)zz < 64u && (unsigned)yy < 64u && (unsigned)xx < 64u)
                    val = *(const unsigned int*)(Xin + (((size_t)zz * 64 + yy) * 64 + xx) * XSTRIDE + 128);
            } else {
                kap = 54 + (slot - 27) * 2;       // zero-fill kappa 54..63
            }
            *(unsigned int*)(ebuf + vox * 72 + kap) = val;
        }
        __syncthreads();
#pragma unroll
        for (int kc = 0; kc < 2; ++kc) {
            bf16x8 bte[2];
#pragma unroll
            for (int nl = 0; nl < 2; ++nl)
                bte[nl] = *(const bf16x8*)(Wfe + (size_t)(kc * 4 + nt2 + nl) * 512 + lane * 8);
#pragma unroll
            for (int ml = 0; ml < 2; ++ml) {
                bf16x8 a = *(const bf16x8*)(ebuf + ((mt2 + ml) * 16 + l16) * 72 + (kc * 4 + quad) * 8);
#pragma unroll
                for (int nl = 0; nl < 2; ++nl)
                    acc[ml][nl] = __builtin_amdgcn_mfma_f32_16x16x32_bf16(a, bte[nl], acc[ml][nl], 0, 0, 0);
            }
        }
        __syncthreads();   // ds_reads drained; rowbuf[1] safe to reuse at it=1
    }

    int p = 0;
    for (int it = 0; it < 9; ++it) {
        // commit prefetched rows into LDS buffer p
#pragma unroll
        for (int i = 0; i < NLD; ++i) {
            int idx = t + i * 256;
            if (idx < 66 * CH16) {
                int xi = idx / CH16, ci = idx % CH16;
                *(uint4*)(&rowbuf[p][xi * LSTRIDE + ci * 8]) = pre[i];
            }
        }
        __syncthreads();
        // issue next iteration's loads (overlaps the MFMA work below)
        if (it < 8) {
            const int itn = it + 1;
            const int zz = z + itn / 3 - 1, yy = y + itn % 3 - 1;
            const bool valid = (unsigned)zz < 64u && (unsigned)yy < 64u;
            const unsigned short* base = Xin + (((size_t)(valid ? zz : 0) * 64 + (valid ? yy : 0)) * 64) * XSTRIDE;
#pragma unroll
            for (int i = 0; i < NLD; ++i) {
                int idx = t + i * 256;
                uint4 val = make_uint4(0u, 0u, 0u, 0u);
                if (idx < 66 * CH16) {
                    int xi = idx / CH16, ci = idx % CH16;
                    int gx = xi - 1;
                    if (valid && gx >= 0 && gx < 64) val = *(const uint4*)(base + gx * XSTRIDE + ci * 8);
                }
                pre[i] = val;
            }
        }
        const unsigned short* rp = rowbuf[p];
#pragma unroll
        for (int dx = 0; dx < 3; ++dx) {
            const int tap = it * 3 + dx;
            const unsigned short* wt = Wf + ((size_t)tap * KC * 4) * 512 + lane * 8;
            bf16x8 bf[KC][2];
#pragma unroll
            for (int kc = 0; kc < KC; ++kc)
#pragma unroll
                for (int nl = 0; nl < 2; ++nl)
                    bf[kc][nl] = *(const bf16x8*)(wt + (size_t)(kc * 4 + nt2 + nl) * 512);
#pragma unroll
            for (int kc = 0; kc < KC; ++kc) {
#pragma unroll
                for (int ml = 0; ml < 2; ++ml) {
                    bf16x8 a = *(const bf16x8*)(&rp[((mt2 + ml) * 16 + l16 + dx) * LSTRIDE + kc * 32 + quad * 8]);
#pragma unroll
                    for (int nl = 0; nl < 2; ++nl)
                        acc[ml][nl] = __builtin_amdgcn_mfma_f32_16x16x32_bf16(a, bf[kc][nl], acc[ml][nl], 0, 0, 0);
                }
            }
        }
        p ^= 1;
    }

    const size_t vbase = ((size_t)z * 64 + y) * 64;
#pragma unroll
    for (int ml = 0; ml < 2; ++ml) {
#pragma unroll
        for (int nl = 0; nl < 2; ++nl) {
            const int oc = (nt2 + nl) * 16 + l16;
            const float bv = Bias[oc];
#pragma unroll
            for (int r = 0; r < 4; ++r)
                Out[(vbase + (mt2 + ml) * 16 + quad * 4 + r) * 64 + oc] = f2bf(acc[ml][nl][r] + bv);
        }
    }
}

// ---------------------------------------------------------------------------
// Per-channel sum / sumsq over all voxels (InstanceNorm stats).
// ---------------------------------------------------------------------------
__global__ __launch_bounds__(256) void stats_kernel(
        const unsigned short* __restrict__ H, float* __restrict__ stats) {
    const int t = threadIdx.x;
    const int c = t & 63, g = t >> 6;
    float s = 0.f, q = 0.f;
    for (int v = blockIdx.x * 4 + g; v < NVOX; v += gridDim.x * 4) {
        float x = bf2f(H[(size_t)v * 64 + c]);
        s += x; q = fmaf(x, x, q);
    }
    __shared__ float ls[256], lq[256];
    ls[t] = s; lq[t] = q;
    __syncthreads();
    if (t < 64) {
        s = ls[t] + ls[t + 64] + ls[t + 128] + ls[t + 192];
        q = lq[t] + lq[t + 64] + lq[t + 128] + lq[t + 192];
        atomicAdd(&stats[c], s);
        atomicAdd(&stats[64 + c], q);
    }
}

__global__ void finalize_kernel(const float* __restrict__ stats, float* __restrict__ musr) {
    int c = threadIdx.x;
    if (c < 64) {
        float mu  = stats[c] * (1.0f / 262144.0f);
        float var = stats[64 + c] * (1.0f / 262144.0f) - mu * mu;
        musr[c] = mu;
        musr[64 + c] = rsqrtf(var + 1e-5f);
    }
}

// ---------------------------------------------------------------------------
// Elementwise InstanceNorm + exact GELU, [v][64] -> [v][64] bf16
// ---------------------------------------------------------------------------
__global__ __launch_bounds__(256) void norm_gelu_kernel(
        const unsigned short* __restrict__ H, const float* __restrict__ musr,
        unsigned short* __restrict__ G) {
    const size_t base = ((size_t)blockIdx.x * 256 + threadIdx.x) * 8;
    uint4 u = *(const uint4*)(H + base);
    const int c0 = (int)(base & 63);
    const unsigned int uu[4] = {u.x, u.y, u.z, u.w};
    unsigned int w[4];
#pragma unroll
    for (int p = 0; p < 4; ++p) {
        int c = c0 + p * 2;
        float x0 = (bflo(uu[p]) - musr[c]) * musr[64 + c];
        float x1 = (bfhi(uu[p]) - musr[c + 1]) * musr[64 + c + 1];
        float g0 = 0.5f * x0 * (1.f + erff(x0 * 0.70710678118f));
        float g1 = 0.5f * x1 * (1.f + erff(x1 * 0.70710678118f));
        w[p] = (unsigned int)f2bf(g0) | ((unsigned int)f2bf(g1) << 16);
    }
    *(uint4*)(G + base) = make_uint4(w[0], w[1], w[2], w[3]);
}

// ---------------------------------------------------------------------------
// Final: InstanceNorm + exact GELU on h2, write fp32 channel planes [64][v].
// ---------------------------------------------------------------------------
__global__ __launch_bounds__(256) void out_final_kernel(
        const unsigned short* __restrict__ H2, const float* __restrict__ musr,
        float* __restrict__ OutEnc) {
    __shared__ float tile[64 * 260];
    const int t = threadIdx.x;
    const size_t v0 = (size_t)blockIdx.x * 256;
#pragma unroll
    for (int i = 0; i < 8; ++i) {
        int chunk = t + i * 256;                  // 0..2047
        uint4 u = *(const uint4*)(H2 + v0 * 64 + (size_t)chunk * 8);
        int vox = chunk >> 3;
        int c0 = (chunk & 7) * 8;
        const unsigned int uu[4] = {u.x, u.y, u.z, u.w};
#pragma unroll
        for (int p = 0; p < 4; ++p) {
            int c = c0 + p * 2;
            float x0 = (bflo(uu[p]) - musr[c]) * musr[64 + c];
            float x1 = (bfhi(uu[p]) - musr[c + 1]) * musr[64 + c + 1];
            tile[c * 260 + vox]       = 0.5f * x0 * (1.f + erff(x0 * 0.70710678118f));
            tile[(c + 1) * 260 + vox] = 0.5f * x1 * (1.f + erff(x1 * 0.70710678118f));
        }
    }
    __syncthreads();
    const int c = t >> 2, sub = t & 3;
#pragma unroll
    for (int iter = 0; iter < 16; ++iter) {
        int fq = iter * 4 + sub;                  // float4 index 0..63
        float4 val = *(const float4*)(&tile[c * 260 + fq * 4]);
        *(float4*)(OutEnc + (size_t)c * NVOX + v0 + fq * 4) = val;
    }
}

// ---------------------------------------------------------------------------
extern "C" void kernel_launch(void* const* d_in, const int* in_sizes, int n_in,
                              void* d_out, int out_size, void* d_ws, size_t ws_size,
                              hipStream_t stream) {
    const void* src  = d_in[0];
    const void* tgt  = d_in[1];
    const void* wsrc = d_in[2];
    const void* bsrc = d_in[3];
    const void* wtgt = d_in[4];
    const void* btgt = d_in[5];
    const void* w1   = d_in[6];
    const void* b1   = d_in[7];
    const void* w2   = d_in[8];
    const void* b2   = d_in[9];
    float* out = (float*)d_out;   // fp32 outputs, 70*262144 elements

    char* ws = (char*)d_ws;
    unsigned short* TPb = (unsigned short*)(ws);                  // 33,554,432 B
    unsigned short* SPb = (unsigned short*)(ws + 33554432);       // 33,554,432 B
    unsigned short* X1  = (unsigned short*)(ws + 67108864);       // 83,886,080 B
    unsigned short* Wf1 = (unsigned short*)(ws + 150994944);      // main+tail frags
    unsigned short* Wf2 = (unsigned short*)(ws + 151547904);      //    221,184 B
    int*   flag   = (int*)  (ws + 151769088);
    float* fbias  = (float*)(ws + 151769152);                     // 256 f32
    float* stats1 = (float*)(ws + 151770176);                     // 128 f32
    float* musr1  = (float*)(ws + 151770688);
    float* stats2 = (float*)(ws + 151771200);
    float* musr2  = (float*)(ws + 151771712);
    unsigned short* H1 = SPb;
    unsigned short* G1 = TPb;
    unsigned short* H2 = X1;
    unsigned short* Wf1e = Wf1 + 27 * 4 * 4 * 512;                // tail frags

    (void)hipMemsetAsync(stats1, 0, 2048, stream);
    sniff_kernel<<<1, 256, 0, stream>>>((const unsigned short*)src, flag);
    prep_kernel<<<1313, 256, 0, stream>>>(w1, w2, bsrc, btgt, b1, b2, flag, Wf1, Wf2, fbias);
    proj_kernel<<<dim3(1024, 2), 256, 0, stream>>>(src, tgt, wsrc, wtgt, fbias, flag, SPb, TPb);
    corr_kernel<<<4096, 256, 0, stream>>>(SPb, TPb, X1, out);
    conv3_kernel<160, 128, 136, 4, 5, true><<<4096, 256, 0, stream>>>(X1, Wf1, Wf1e, fbias + 128, H1);
    stats_kernel<<<256, 256, 0, stream>>>(H1, stats1);
    finalize_kernel<<<1, 64, 0, stream>>>(stats1, musr1);
    norm_gelu_kernel<<<8192, 256, 0, stream>>>(H1, musr1, G1);
    conv3_kernel<64, 64, 72, 2, 3, false><<<4096, 256, 0, stream>>>(G1, Wf2, nullptr, fbias + 192, H2);
    stats_kernel<<<256, 256, 0, stream>>>(H2, stats2);
    finalize_kernel<<<1, 64, 0, stream>>>(stats2, musr2);
    out_final_kernel<<<1024, 256, 0, stream>>>(H2, musr2, out + 6 * (size_t)NVOX);
}